// Round 1
// 188.491 us; speedup vs baseline: 1.0425x; 1.0425x over previous
//
#include <hip/hip_runtime.h>
#include <hip/hip_bf16.h>
#include <stdint.h>

typedef short short8 __attribute__((ext_vector_type(8)));
typedef float f32x4  __attribute__((ext_vector_type(4)));
typedef float f32x2  __attribute__((ext_vector_type(2)));
typedef float f32x16 __attribute__((ext_vector_type(16)));
typedef int   i32x4  __attribute__((ext_vector_type(4)));
typedef int   i32x8  __attribute__((ext_vector_type(8)));
typedef unsigned char uchar;

#define B_ 2
#define C_ 512
#define N_ 4096
#define G_ 32
#define WN (C_ * C_)
#define PREP_BLOCKS 4101   // ceil((4*WN + 1024)/256)

static __device__ __forceinline__ short f2bf(float f) {
    return __builtin_bit_cast(short, __float2bfloat16(f));
}
static __device__ __forceinline__ uchar f2fp8(float f) {
    return (uchar)(__builtin_amdgcn_cvt_pk_fp8_f32(f, f, 0, false) & 0xff);
}

// async global->LDS DMA, 16 B/lane. LDS dest = wave-uniform base + lane*16.
static __device__ __forceinline__ void async16(uchar* lds_wave_base, const uchar* g) {
    auto l  = (__attribute__((address_space(3))) unsigned int*)(uintptr_t)(lds_wave_base);
    auto gg = (const __attribute__((address_space(1))) unsigned int*)(g);
    __builtin_amdgcn_global_load_lds(gg, l, 16, 0, 0);
}

// ---- merged prep + gn partial stats (no atomics: each stats block owns a slot) ----
__global__ void prep_stats(const float* __restrict__ wq, const float* __restrict__ wk,
                           const float* __restrict__ wv, const float* __restrict__ wp,
                           const float* __restrict__ bq, const float* __restrict__ bk,
                           const float* __restrict__ x,
                           uchar* __restrict__ Wb, float* __restrict__ bqk,
                           float* __restrict__ raw) {
    if (blockIdx.x < PREP_BLOCKS) {
        int i = blockIdx.x * 256 + threadIdx.x;
        if (i < 4 * WN) {
            const float* src = (i < 2*WN) ? ((i < WN) ? wq : wk) : ((i < 3*WN) ? wv : wp);
            Wb[i] = f2fp8(src[i & (WN - 1)] * 16.f);
        } else if (i < 4*WN + 1024) {
            int j = i - 4*WN;
            bqk[j] = (j < C_) ? bq[j] : bk[j - C_];
        }
        return;
    }
    const int idx = blockIdx.x - PREP_BLOCKS;        // 0..255
    const int bg = idx >> 2, qt = idx & 3;
    const float4* p = (const float4*)(x + (size_t)bg * 16 * N_ + (size_t)qt * 4 * N_);
    int tid = threadIdx.x;
    float s = 0.f, sq = 0.f;
    #pragma unroll
    for (int rep = 0; rep < 16; rep++) {
        float4 t = p[rep * 256 + tid];
        s  += t.x + t.y + t.z + t.w;
        sq += t.x*t.x + t.y*t.y + t.z*t.z + t.w*t.w;
    }
    __shared__ float rs[256], rq[256];
    rs[tid] = s; rq[tid] = sq;
    __syncthreads();
    for (int h = 128; h > 0; h >>= 1) {
        if (tid < h) { rs[tid] += rs[tid+h]; rq[tid] += rq[tid+h]; }
        __syncthreads();
    }
    if (tid == 0) {
        raw[idx*2+0] = rs[0];
        raw[idx*2+1] = rq[0];
    }
}

// ---- groupnorm apply + transpose: x[b,c,n] fp32 -> Hn[b,n,c] fp8 ----
__global__ void gn_apply(const float* __restrict__ x, const float* __restrict__ raw,
                         const float* __restrict__ gw, const float* __restrict__ gb,
                         uchar* __restrict__ hn) {
    __shared__ uchar t[64 * 68];
    const int n0 = blockIdx.x * 64, c0 = blockIdx.y * 64, b = blockIdx.z;
    const int lane = threadIdx.x & 63, w = threadIdx.x >> 6;
    const float inv = 1.f / (16.f * N_);
    #pragma unroll
    for (int rep = 0; rep < 16; rep++) {
        int c  = rep * 4 + w;
        int cc = c0 + c;
        int g  = cc >> 4;
        int base = (b*G_ + g) * 8;
        float mean = (raw[base] + raw[base+2] + raw[base+4] + raw[base+6]) * inv;
        float var  = (raw[base+1] + raw[base+3] + raw[base+5] + raw[base+7]) * inv - mean * mean;
        float rstd = rsqrtf(var + 1e-6f);
        float sc = gw[cc] * rstd;
        float bi = gb[cc] - mean * sc;
        float v = x[((size_t)(b*C_ + cc)) * N_ + n0 + lane];
        t[lane*68 + c] = f2fp8(v * sc + bi);
    }
    __syncthreads();
    #pragma unroll
    for (int rep = 0; rep < 16; rep++) {
        int n = rep * 4 + w;
        hn[((size_t)(b*N_ + n0 + n)) * C_ + c0 + lane] = t[n*68 + lane];
    }
}

// ---- fp8 NT GEMM, MX-scaled MFMA (32x32x64 f8f6f4, unit scales) ----
// C[m,n] = alpha * sum_k A[m,k]*B[n,k] (+bias) (+residual)
// A,B fp8 e4m3; lda/ldb/sAz/sBz in BYTES; ldc/sCz in elements. BK=64.
// Staging: 3-buffer LDS ring, tile t+2 DMA'd at start of step t (prefetch ~2
// steps in flight). Barrier waits only s_waitcnt vmcnt(D) (own share of the
// oldest prefetched tile) — deeper prefetch never drained (AITER pattern).
// LDS layout: 16B-slot s of row r holds global chunk s ^ ((r>>1)&3) (swizzle
// applied on DMA SOURCE address; DMA dest is linear lane*16).
// MFMA fragments: per lane row = lane&31, K-bytes = (lane>>5)*32 + 0..31,
// read as 2x ds_read_b128 at slots (hk^sw), (hk^sw)^1 — conflict-free under
// the store swizzle (consecutive 8 lanes cover all 8 bank-quads).
// Scales: e8m0 127 (=1.0) both operands, opsel 0 -> byte 0.
// BIAS_MODE: 0 none, 1 per-col, 2 per-row. OUT_MODE: 0 bf16, 2 fp32+res, 3 fp8.
// SWZ: XCD-aware flat-grid decode (grid.x = 4*64*2, siblings-on-one-XCD).
template<int BM, int BIAS_MODE, int OUT_MODE, int K, int SWZ>
__global__ __launch_bounds__(256, 2)
void gemm_nt8(const uchar* __restrict__ A, int lda, long long sAz,
              const uchar* __restrict__ Bm, int ldb, long long sBz,
              void* __restrict__ Cv, int ldc, long long sCz,
              const float* __restrict__ bias,
              const float* __restrict__ res,
              float alpha) {
    constexpr int MI = BM / 64;                      // 32-row fragments per wave
    constexpr int T  = K / 64;
    constexpr int D  = (BM == 128) ? 4 : 3;          // DMAs per wave per tile
    constexpr unsigned WAITD = 0xF70u | D;           // vmcnt(D) expcnt(7) lgkm(15)
    constexpr unsigned WAIT0 = 0xF70u;               // vmcnt(0)
    __shared__ uchar As[3][BM * 64];
    __shared__ uchar Bs[3][128 * 64];

    int bx, by, bz;
    if (SWZ) {
        int fid = blockIdx.x;
        int xcd = fid & 7, j = fid >> 3;
        int gg = (j >> 2) * 8 + xcd;                 // sibling group
        bx = j & 3; by = gg & 63; bz = gg >> 6;
    } else { bx = blockIdx.x; by = blockIdx.y; bz = blockIdx.z; }

    const int tid  = threadIdx.x;
    const int lane = tid & 63;
    const int wid  = tid >> 6;
    const int wr   = wid >> 1;
    const int wc   = wid & 1;
    const int m0 = by * BM;
    const int n0 = bx * 128;

    // DMA source: thread (r=tid>>2, c=tid&3) fetches global 16B chunk c^((r>>1)&3)
    const int r  = tid >> 2;
    const int gc = (tid & 3) ^ ((r >> 1) & 3);
    const uchar* Ap  = A  + sAz * bz + (size_t)(m0 + r) * lda + gc * 16;
    const uchar* Ap1 = Ap + (size_t)64 * lda;
    const uchar* Bp  = Bm + sBz * bz + (size_t)(n0 + r) * ldb + gc * 16;
    const uchar* Bp1 = Bp + (size_t)64 * ldb;

    f32x16 acc[MI][2];
    #pragma unroll
    for (int i = 0; i < MI; i++)
        #pragma unroll
        for (int j = 0; j < 2; j++)
            #pragma unroll
            for (int e = 0; e < 16; e++)
                acc[i][j][e] = 0.f;

    const int rl = lane & 31;                        // fragment row
    const int hk = (lane >> 5) * 2;                  // logical 16B-slot of K-half

    #define ISSUE(IB, u) do { size_t _kb = (size_t)(u) * 64; \
        async16(&As[IB][wid * 1024], Ap + _kb); \
        if (BM == 128) async16(&As[IB][4096 + wid * 1024], Ap1 + _kb); \
        async16(&Bs[IB][wid * 1024], Bp + _kb); \
        async16(&Bs[IB][4096 + wid * 1024], Bp1 + _kb); } while (0)

    #define STEP(Bf, DO_ISSUE, IB, u, DO_BAR, WIMM) do { \
        i32x8 af[MI], bf[2]; \
        _Pragma("unroll") \
        for (int i = 0; i < MI; i++) { \
            int ar = wr*(BM/2) + i*32 + rl; \
            int ao = ar*64 + ((hk ^ ((ar>>1)&3)) << 4); \
            *(i32x4*)&af[i]       = *(const i32x4*)&As[Bf][ao]; \
            *(((i32x4*)&af[i])+1) = *(const i32x4*)&As[Bf][ao ^ 16]; \
        } \
        _Pragma("unroll") \
        for (int i = 0; i < 2; i++) { \
            int br = wc*64 + i*32 + rl; \
            int bo = br*64 + ((hk ^ ((br>>1)&3)) << 4); \
            *(i32x4*)&bf[i]       = *(const i32x4*)&Bs[Bf][bo]; \
            *(((i32x4*)&bf[i])+1) = *(const i32x4*)&Bs[Bf][bo ^ 16]; \
        } \
        if (DO_ISSUE) ISSUE(IB, u); \
        _Pragma("unroll") \
        for (int mi = 0; mi < MI; mi++) \
            _Pragma("unroll") \
            for (int ni = 0; ni < 2; ni++) \
                acc[mi][ni] = __builtin_amdgcn_mfma_scale_f32_32x32x64_f8f6f4( \
                    af[mi], bf[ni], acc[mi][ni], 0, 0, 0, 127, 0, 127); \
        if (DO_BAR) { __builtin_amdgcn_s_waitcnt(WIMM); __builtin_amdgcn_s_barrier(); } \
    } while (0)

    // prologue: tiles 0,1 in flight; wait own share of tile 0, barrier
    ISSUE(0, 0);
    ISSUE(1, 1);
    __builtin_amdgcn_s_waitcnt(WAITD);
    __builtin_amdgcn_s_barrier();

    constexpr int Gm = (T - 2) / 3;                  // T=8 -> 2, T=64 -> 20
    for (int m = 0; m < Gm; m++) {
        STEP(0, 1, 2, m*3 + 2, 1, WAITD);
        STEP(1, 1, 0, m*3 + 3, 1, WAITD);
        STEP(2, 1, 1, m*3 + 4, 1, WAITD);
    }
    if (T - 3*Gm == 2) {                             // T=8: steps 6,7
        STEP(0, 0, 0, 0, 1, WAIT0);
        STEP(1, 0, 0, 0, 0, 0);
    } else {                                         // T=64: steps 60..63
        STEP(0, 1, 2, T-2, 1, WAITD);
        STEP(1, 1, 0, T-1, 1, WAITD);
        STEP(2, 0, 0, 0, 1, WAIT0);
        STEP(0, 0, 0, 0, 0, 0);
    }
    #undef ISSUE
    #undef STEP

    // C/D 32x32 layout: col=lane&31, row=(reg&3)+8*(reg>>2)+4*(lane>>5)
    const int rh = (lane >> 5) * 4;
    #pragma unroll
    for (int mi = 0; mi < MI; mi++) {
        #pragma unroll
        for (int ni = 0; ni < 2; ni++) {
            int cc = n0 + wc*64 + ni*32 + rl;
            float cb = (BIAS_MODE == 1) ? bias[cc] : 0.f;
            #pragma unroll
            for (int g = 0; g < 4; g++) {
                #pragma unroll
                for (int r4 = 0; r4 < 4; r4++) {
                    int rr = m0 + wr*(BM/2) + mi*32 + g*8 + rh + r4;
                    float val = acc[mi][ni][g*4 + r4] * alpha + cb;
                    if (BIAS_MODE == 2) val += bias[rr];
                    long long idx = sCz * bz + (long long)rr * ldc + cc;
                    if (OUT_MODE == 0)      ((short*)Cv)[idx] = f2bf(val);
                    else if (OUT_MODE == 2) ((float*)Cv)[idx] = val + res[idx];
                    else                    ((uchar*)Cv)[idx] = f2fp8(val);
                }
            }
        }
    }
}

// ---- softmax: one wave per row; fp8(S*16) in, fp8(P*256) out, in place ----
__global__ void softmax_rows8(uchar* __restrict__ S) {
    const int lane = threadIdx.x & 63;
    const int wave = threadIdx.x >> 6;
    const size_t row = (size_t)blockIdx.x * 4 + wave;   // 0..8191
    uint4* rp = (uint4*)(S + row * N_);                 // 256 uint4 per row
    uint4 d[4];
    float f[64];
    float mx = -3.0e38f;
    #pragma unroll
    for (int c = 0; c < 4; c++) {
        d[c] = rp[c * 64 + lane];
        unsigned wv[4] = {d[c].x, d[c].y, d[c].z, d[c].w};
        #pragma unroll
        for (int u = 0; u < 4; u++) {
            f32x2 lo = __builtin_amdgcn_cvt_pk_f32_fp8(wv[u], false);
            f32x2 hi = __builtin_amdgcn_cvt_pk_f32_fp8(wv[u], true);
            int b = c*16 + u*4;
            f[b+0] = lo[0]; f[b+1] = lo[1]; f[b+2] = hi[0]; f[b+3] = hi[1];
            mx = fmaxf(mx, fmaxf(fmaxf(lo[0], lo[1]), fmaxf(hi[0], hi[1])));
        }
    }
    #pragma unroll
    for (int off = 32; off > 0; off >>= 1)
        mx = fmaxf(mx, __shfl_xor(mx, off));
    float sum = 0.f;
    const float k = 0.0625f;                            // decoded = S*16
    #pragma unroll
    for (int j = 0; j < 64; j++) { f[j] = __expf((f[j] - mx) * k); sum += f[j]; }
    #pragma unroll
    for (int off = 32; off > 0; off >>= 1)
        sum += __shfl_xor(sum, off);
    float inv = 256.f / sum;                            // store P*256 fp8
    #pragma unroll
    for (int c = 0; c < 4; c++) {
        unsigned wv[4];
        #pragma unroll
        for (int u = 0; u < 4; u++) {
            int b = c*16 + u*4;
            int o = 0;
            o = __builtin_amdgcn_cvt_pk_fp8_f32(f[b+0]*inv, f[b+1]*inv, o, false);
            o = __builtin_amdgcn_cvt_pk_fp8_f32(f[b+2]*inv, f[b+3]*inv, o, true);
            wv[u] = (unsigned)o;
        }
        uint4 ov; ov.x = wv[0]; ov.y = wv[1]; ov.z = wv[2]; ov.w = wv[3];
        rp[c * 64 + lane] = ov;
    }
}

extern "C" void kernel_launch(void* const* d_in, const int* in_sizes, int n_in,
                              void* d_out, int out_size, void* d_ws, size_t ws_size,
                              hipStream_t stream) {
    const float* x   = (const float*)d_in[0];
    const float* gnw = (const float*)d_in[1];
    const float* gnb = (const float*)d_in[2];
    const float* wq  = (const float*)d_in[3];
    const float* bq  = (const float*)d_in[4];
    const float* wk  = (const float*)d_in[5];
    const float* bk  = (const float*)d_in[6];
    const float* wv  = (const float*)d_in[7];
    const float* bv  = (const float*)d_in[8];
    const float* wp  = (const float*)d_in[9];
    const float* bp  = (const float*)d_in[10];
    float* out = (float*)d_out;
    char*  ws  = (char*)d_ws;

    // workspace layout (~56 MB)
    float* raw = (float*)(ws + 0);                   // 2 KB  gn stat partials [64][4][2]
    float* bqk = (float*)(ws + 8192);                // 4 KB
    uchar* Wb  = (uchar*)(ws + 65536);               // 1 MB  [4][512][512] fp8 (x16)
    uchar* Hn  = (uchar*)(ws + (2ull  << 20));       // 4 MB  [2][4096][512] fp8
    uchar* QK8 = (uchar*)(ws + (8ull  << 20));       // 8 MB  [2][4096][1024] fp8 (Q|K)
    uchar* V8  = (uchar*)(ws + (16ull << 20));       // 4 MB  [2][512][4096] fp8
    uchar* Ot8 = (uchar*)(ws + (20ull << 20));       // 4 MB  [2][4096][512] fp8 (x16)
    uchar* Sb  = (uchar*)(ws + (24ull << 20));       // 32 MB [2][4096][4096] fp8 (S*16 -> P*256)

    prep_stats<<<PREP_BLOCKS + 256, 256, 0, stream>>>(wq, wk, wv, wp, bq, bk, x, Wb, bqk, raw);
    gn_apply<<<dim3(N_/64, C_/64, B_), 256, 0, stream>>>(x, raw, gnw, gnb, Hn);

    const long long sHn = (long long)N_ * C_;        // bytes (fp8)
    const long long sQK = (long long)N_ * 1024;
    const long long sV  = (long long)C_ * N_;
    const long long sS  = (long long)N_ * N_;

    // QK fused: [4096,1024] = (Hn @ [Wq;Wk]^T)/16 + bqk -> fp8   (512 blocks)
    gemm_nt8<128,1,3,512,0><<<dim3(8, 32, 2), 256, 0, stream>>>(
        Hn, C_, sHn, Wb, C_, 0, QK8, 1024, sQK, bqk, nullptr, 1.f/16.f);
    // V: [512,4096] = (Wv @ Hn^T)/16 + bv -> fp8   (512 blocks)
    gemm_nt8<64,2,3,512,0><<<dim3(32, 8, 2), 256, 0, stream>>>(
        Wb + 2*WN, C_, 0, Hn, C_, sHn, V8, N_, sV, bv, nullptr, 1.f/16.f);

    // S*16 = Q @ K^T * (scale*16) -> fp8, both batches (2048 blocks)
    const float alphaS = 0.044194173824159216f * 16.f;   // 512^-0.5 * 16
    gemm_nt8<128,0,3,512,0><<<dim3(32, 32, 2), 256, 0, stream>>>(
        QK8, 1024, sQK, QK8 + 512, 1024, sQK, Sb, N_, sS, nullptr, nullptr, alphaS);
    // softmax rows: fp8 in/out in place (2048 blocks)
    softmax_rows8<<<B_*N_/4, 256, 0, stream>>>(Sb);
    // Ot = (P8 @ V8^T) * 16/256 -> fp8 (x16)  (512 blocks, XCD-swizzled flat grid)
    gemm_nt8<64,0,3,4096,1><<<512, 256, 0, stream>>>(
        Sb, N_, sS, V8, N_, sV, Ot8, C_, sHn, nullptr, nullptr, 1.f/16.f);
    // out[b,o,n] = x + (Wp @ Ot^T)/256 + bp   (512 blocks)
    gemm_nt8<64,2,2,512,0><<<dim3(32, 8, 2), 256, 0, stream>>>(
        Wb + 3*WN, C_, 0, Ot8, C_, sHn, out, N_, (long long)C_*N_, bp, x, 1.f/256.f);
}

// Round 2
// 187.967 us; speedup vs baseline: 1.0454x; 1.0028x over previous
//
#include <hip/hip_runtime.h>
#include <hip/hip_bf16.h>
#include <stdint.h>

typedef short short8 __attribute__((ext_vector_type(8)));
typedef float f32x4  __attribute__((ext_vector_type(4)));
typedef float f32x2  __attribute__((ext_vector_type(2)));
typedef float f32x16 __attribute__((ext_vector_type(16)));
typedef int   i32x4  __attribute__((ext_vector_type(4)));
typedef int   i32x8  __attribute__((ext_vector_type(8)));
typedef unsigned char uchar;

#define B_ 2
#define C_ 512
#define N_ 4096
#define G_ 32
#define WN (C_ * C_)
#define PREP_BLOCKS 4101   // ceil((4*WN + 1024)/256)

static __device__ __forceinline__ short f2bf(float f) {
    return __builtin_bit_cast(short, __float2bfloat16(f));
}
static __device__ __forceinline__ uchar f2fp8(float f) {
    return (uchar)(__builtin_amdgcn_cvt_pk_fp8_f32(f, f, 0, false) & 0xff);
}

// async global->LDS DMA, 16 B/lane. LDS dest = wave-uniform base + lane*16.
static __device__ __forceinline__ void async16(uchar* lds_wave_base, const uchar* g) {
    auto l  = (__attribute__((address_space(3))) unsigned int*)(uintptr_t)(lds_wave_base);
    auto gg = (const __attribute__((address_space(1))) unsigned int*)(g);
    __builtin_amdgcn_global_load_lds(gg, l, 16, 0, 0);
}

// ---- merged prep + gn partial stats (no atomics: each stats block owns a slot) ----
__global__ void prep_stats(const float* __restrict__ wq, const float* __restrict__ wk,
                           const float* __restrict__ wv, const float* __restrict__ wp,
                           const float* __restrict__ bq, const float* __restrict__ bk,
                           const float* __restrict__ x,
                           uchar* __restrict__ Wb, float* __restrict__ bqk,
                           float* __restrict__ raw) {
    if (blockIdx.x < PREP_BLOCKS) {
        int i = blockIdx.x * 256 + threadIdx.x;
        if (i < 4 * WN) {
            const float* src = (i < 2*WN) ? ((i < WN) ? wq : wk) : ((i < 3*WN) ? wv : wp);
            Wb[i] = f2fp8(src[i & (WN - 1)] * 16.f);
        } else if (i < 4*WN + 1024) {
            int j = i - 4*WN;
            bqk[j] = (j < C_) ? bq[j] : bk[j - C_];
        }
        return;
    }
    const int idx = blockIdx.x - PREP_BLOCKS;        // 0..255
    const int bg = idx >> 2, qt = idx & 3;
    const float4* p = (const float4*)(x + (size_t)bg * 16 * N_ + (size_t)qt * 4 * N_);
    int tid = threadIdx.x;
    float s = 0.f, sq = 0.f;
    #pragma unroll
    for (int rep = 0; rep < 16; rep++) {
        float4 t = p[rep * 256 + tid];
        s  += t.x + t.y + t.z + t.w;
        sq += t.x*t.x + t.y*t.y + t.z*t.z + t.w*t.w;
    }
    __shared__ float rs[256], rq[256];
    rs[tid] = s; rq[tid] = sq;
    __syncthreads();
    for (int h = 128; h > 0; h >>= 1) {
        if (tid < h) { rs[tid] += rs[tid+h]; rq[tid] += rq[tid+h]; }
        __syncthreads();
    }
    if (tid == 0) {
        raw[idx*2+0] = rs[0];
        raw[idx*2+1] = rq[0];
    }
}

// ---- groupnorm apply + transpose: x[b,c,n] fp32 -> Hn[b,n,c] fp8 ----
__global__ void gn_apply(const float* __restrict__ x, const float* __restrict__ raw,
                         const float* __restrict__ gw, const float* __restrict__ gb,
                         uchar* __restrict__ hn) {
    __shared__ uchar t[64 * 68];
    const int n0 = blockIdx.x * 64, c0 = blockIdx.y * 64, b = blockIdx.z;
    const int lane = threadIdx.x & 63, w = threadIdx.x >> 6;
    const float inv = 1.f / (16.f * N_);
    #pragma unroll
    for (int rep = 0; rep < 16; rep++) {
        int c  = rep * 4 + w;
        int cc = c0 + c;
        int g  = cc >> 4;
        int base = (b*G_ + g) * 8;
        float mean = (raw[base] + raw[base+2] + raw[base+4] + raw[base+6]) * inv;
        float var  = (raw[base+1] + raw[base+3] + raw[base+5] + raw[base+7]) * inv - mean * mean;
        float rstd = rsqrtf(var + 1e-6f);
        float sc = gw[cc] * rstd;
        float bi = gb[cc] - mean * sc;
        float v = x[((size_t)(b*C_ + cc)) * N_ + n0 + lane];
        t[lane*68 + c] = f2fp8(v * sc + bi);
    }
    __syncthreads();
    #pragma unroll
    for (int rep = 0; rep < 16; rep++) {
        int n = rep * 4 + w;
        hn[((size_t)(b*N_ + n0 + n)) * C_ + c0 + lane] = t[n*68 + lane];
    }
}

// ---- fp8 NT GEMM, MX-scaled MFMA (32x32x64 f8f6f4, unit scales) ----
// C[m,n] = alpha * sum_k A[m,k]*B[n,k] (+bias) (+residual)
// A,B fp8 e4m3; lda/ldb/sAz/sBz in BYTES; ldc/sCz in elements. BK=64.
// Staging: 3-buffer LDS ring, tile t+2 DMA'd at start of step t (prefetch ~2
// steps in flight). Barrier waits only s_waitcnt vmcnt(D) (own share of the
// oldest prefetched tile) — deeper prefetch never drained (AITER pattern).
// LDS layout: 16B-slot s of row r holds global chunk s ^ ((r>>1)&3) (swizzle
// applied on DMA SOURCE address; DMA dest is linear lane*16).
// MFMA fragments: per lane row = lane&31, K-bytes = (lane>>5)*32 + 0..31,
// read as 2x ds_read_b128 at slots (hk^sw), (hk^sw)^1 — conflict-free under
// the store swizzle (consecutive 8 lanes cover all 8 bank-quads).
// Scales: e8m0 127 (=1.0) both operands, opsel 0 -> byte 0.
// Occupancy: __launch_bounds__(256,3) -> 3 blocks/CU (LDS 144/108 KB of 160).
// BIAS_MODE: 0 none, 1 per-col, 2 per-row. OUT_MODE: 0 bf16, 2 fp32+res, 3 fp8.
// SWZ: 0 = 3D grid; 1 = PV flat decode (grid 512); 2 = S flat decode
//      (grid 2048: XCD x owns by in [4x,4x+4) x all bx -> ~2.25 MB/XCD L2 set).
template<int BM, int BIAS_MODE, int OUT_MODE, int K, int SWZ>
__global__ __launch_bounds__(256, 3)
void gemm_nt8(const uchar* __restrict__ A, int lda, long long sAz,
              const uchar* __restrict__ Bm, int ldb, long long sBz,
              void* __restrict__ Cv, int ldc, long long sCz,
              const float* __restrict__ bias,
              const float* __restrict__ res,
              float alpha) {
    constexpr int MI = BM / 64;                      // 32-row fragments per wave
    constexpr int T  = K / 64;
    constexpr int D  = (BM == 128) ? 4 : 3;          // DMAs per wave per tile
    constexpr unsigned WAITD = 0xF70u | D;           // vmcnt(D) expcnt(7) lgkm(15)
    constexpr unsigned WAIT0 = 0xF70u;               // vmcnt(0)
    __shared__ uchar As[3][BM * 64];
    __shared__ uchar Bs[3][128 * 64];

    int bx, by, bz;
    if (SWZ == 1) {
        int fid = blockIdx.x;
        int xcd = fid & 7, j = fid >> 3;
        int gg = (j >> 2) * 8 + xcd;                 // sibling group
        bx = j & 3; by = gg & 63; bz = gg >> 6;
    } else if (SWZ == 2) {
        int fid = blockIdx.x;                        // 0..2047
        int xcd = fid & 7, j = fid >> 3;             // j 0..255
        bz = j >> 7;
        int r = j & 127;
        by = (xcd << 2) | (r >> 5);                  // XCD owns a 4-row band
        bx = r & 31;
    } else { bx = blockIdx.x; by = blockIdx.y; bz = blockIdx.z; }

    const int tid  = threadIdx.x;
    const int lane = tid & 63;
    const int wid  = tid >> 6;
    const int wr   = wid >> 1;
    const int wc   = wid & 1;
    const int m0 = by * BM;
    const int n0 = bx * 128;

    // DMA source: thread (r=tid>>2, c=tid&3) fetches global 16B chunk c^((r>>1)&3)
    const int r  = tid >> 2;
    const int gc = (tid & 3) ^ ((r >> 1) & 3);
    const uchar* Ap  = A  + sAz * bz + (size_t)(m0 + r) * lda + gc * 16;
    const uchar* Ap1 = Ap + (size_t)64 * lda;
    const uchar* Bp  = Bm + sBz * bz + (size_t)(n0 + r) * ldb + gc * 16;
    const uchar* Bp1 = Bp + (size_t)64 * ldb;

    f32x16 acc[MI][2];
    #pragma unroll
    for (int i = 0; i < MI; i++)
        #pragma unroll
        for (int j = 0; j < 2; j++)
            #pragma unroll
            for (int e = 0; e < 16; e++)
                acc[i][j][e] = 0.f;

    const int rl = lane & 31;                        // fragment row
    const int hk = (lane >> 5) * 2;                  // logical 16B-slot of K-half

    #define ISSUE(IB, u) do { size_t _kb = (size_t)(u) * 64; \
        async16(&As[IB][wid * 1024], Ap + _kb); \
        if (BM == 128) async16(&As[IB][4096 + wid * 1024], Ap1 + _kb); \
        async16(&Bs[IB][wid * 1024], Bp + _kb); \
        async16(&Bs[IB][4096 + wid * 1024], Bp1 + _kb); } while (0)

    #define STEP(Bf, DO_ISSUE, IB, u, DO_BAR, WIMM) do { \
        i32x8 af[MI], bf[2]; \
        _Pragma("unroll") \
        for (int i = 0; i < MI; i++) { \
            int ar = wr*(BM/2) + i*32 + rl; \
            int ao = ar*64 + ((hk ^ ((ar>>1)&3)) << 4); \
            *(i32x4*)&af[i]       = *(const i32x4*)&As[Bf][ao]; \
            *(((i32x4*)&af[i])+1) = *(const i32x4*)&As[Bf][ao ^ 16]; \
        } \
        _Pragma("unroll") \
        for (int i = 0; i < 2; i++) { \
            int br = wc*64 + i*32 + rl; \
            int bo = br*64 + ((hk ^ ((br>>1)&3)) << 4); \
            *(i32x4*)&bf[i]       = *(const i32x4*)&Bs[Bf][bo]; \
            *(((i32x4*)&bf[i])+1) = *(const i32x4*)&Bs[Bf][bo ^ 16]; \
        } \
        if (DO_ISSUE) ISSUE(IB, u); \
        _Pragma("unroll") \
        for (int mi = 0; mi < MI; mi++) \
            _Pragma("unroll") \
            for (int ni = 0; ni < 2; ni++) \
                acc[mi][ni] = __builtin_amdgcn_mfma_scale_f32_32x32x64_f8f6f4( \
                    af[mi], bf[ni], acc[mi][ni], 0, 0, 0, 127, 0, 127); \
        if (DO_BAR) { __builtin_amdgcn_s_waitcnt(WIMM); __builtin_amdgcn_s_barrier(); } \
    } while (0)

    // prologue: tiles 0,1 in flight; wait own share of tile 0, barrier
    ISSUE(0, 0);
    ISSUE(1, 1);
    __builtin_amdgcn_s_waitcnt(WAITD);
    __builtin_amdgcn_s_barrier();

    constexpr int Gm = (T - 2) / 3;                  // T=8 -> 2, T=64 -> 20
    for (int m = 0; m < Gm; m++) {
        STEP(0, 1, 2, m*3 + 2, 1, WAITD);
        STEP(1, 1, 0, m*3 + 3, 1, WAITD);
        STEP(2, 1, 1, m*3 + 4, 1, WAITD);
    }
    if (T - 3*Gm == 2) {                             // T=8: steps 6,7
        STEP(0, 0, 0, 0, 1, WAIT0);
        STEP(1, 0, 0, 0, 0, 0);
    } else {                                         // T=64: steps 60..63
        STEP(0, 1, 2, T-2, 1, WAITD);
        STEP(1, 1, 0, T-1, 1, WAITD);
        STEP(2, 0, 0, 0, 1, WAIT0);
        STEP(0, 0, 0, 0, 0, 0);
    }
    #undef ISSUE
    #undef STEP

    // C/D 32x32 layout: col=lane&31, row=(reg&3)+8*(reg>>2)+4*(lane>>5)
    const int rh = (lane >> 5) * 4;
    #pragma unroll
    for (int mi = 0; mi < MI; mi++) {
        #pragma unroll
        for (int ni = 0; ni < 2; ni++) {
            int cc = n0 + wc*64 + ni*32 + rl;
            float cb = (BIAS_MODE == 1) ? bias[cc] : 0.f;
            #pragma unroll
            for (int g = 0; g < 4; g++) {
                #pragma unroll
                for (int r4 = 0; r4 < 4; r4++) {
                    int rr = m0 + wr*(BM/2) + mi*32 + g*8 + rh + r4;
                    float val = acc[mi][ni][g*4 + r4] * alpha + cb;
                    if (BIAS_MODE == 2) val += bias[rr];
                    long long idx = sCz * bz + (long long)rr * ldc + cc;
                    if (OUT_MODE == 0)      ((short*)Cv)[idx] = f2bf(val);
                    else if (OUT_MODE == 2) ((float*)Cv)[idx] = val + res[idx];
                    else                    ((uchar*)Cv)[idx] = f2fp8(val);
                }
            }
        }
    }
}

// ---- softmax: one wave per row; fp8(S*16) in, fp8(P*256) out, in place ----
__global__ void softmax_rows8(uchar* __restrict__ S) {
    const int lane = threadIdx.x & 63;
    const int wave = threadIdx.x >> 6;
    const size_t row = (size_t)blockIdx.x * 4 + wave;   // 0..8191
    uint4* rp = (uint4*)(S + row * N_);                 // 256 uint4 per row
    uint4 d[4];
    float f[64];
    float mx = -3.0e38f;
    #pragma unroll
    for (int c = 0; c < 4; c++) {
        d[c] = rp[c * 64 + lane];
        unsigned wv[4] = {d[c].x, d[c].y, d[c].z, d[c].w};
        #pragma unroll
        for (int u = 0; u < 4; u++) {
            f32x2 lo = __builtin_amdgcn_cvt_pk_f32_fp8(wv[u], false);
            f32x2 hi = __builtin_amdgcn_cvt_pk_f32_fp8(wv[u], true);
            int b = c*16 + u*4;
            f[b+0] = lo[0]; f[b+1] = lo[1]; f[b+2] = hi[0]; f[b+3] = hi[1];
            mx = fmaxf(mx, fmaxf(fmaxf(lo[0], lo[1]), fmaxf(hi[0], hi[1])));
        }
    }
    #pragma unroll
    for (int off = 32; off > 0; off >>= 1)
        mx = fmaxf(mx, __shfl_xor(mx, off));
    float sum = 0.f;
    const float k = 0.0625f;                            // decoded = S*16
    #pragma unroll
    for (int j = 0; j < 64; j++) { f[j] = __expf((f[j] - mx) * k); sum += f[j]; }
    #pragma unroll
    for (int off = 32; off > 0; off >>= 1)
        sum += __shfl_xor(sum, off);
    float inv = 256.f / sum;                            // store P*256 fp8
    #pragma unroll
    for (int c = 0; c < 4; c++) {
        unsigned wv[4];
        #pragma unroll
        for (int u = 0; u < 4; u++) {
            int b = c*16 + u*4;
            int o = 0;
            o = __builtin_amdgcn_cvt_pk_fp8_f32(f[b+0]*inv, f[b+1]*inv, o, false);
            o = __builtin_amdgcn_cvt_pk_fp8_f32(f[b+2]*inv, f[b+3]*inv, o, true);
            wv[u] = (unsigned)o;
        }
        uint4 ov; ov.x = wv[0]; ov.y = wv[1]; ov.z = wv[2]; ov.w = wv[3];
        rp[c * 64 + lane] = ov;
    }
}

extern "C" void kernel_launch(void* const* d_in, const int* in_sizes, int n_in,
                              void* d_out, int out_size, void* d_ws, size_t ws_size,
                              hipStream_t stream) {
    const float* x   = (const float*)d_in[0];
    const float* gnw = (const float*)d_in[1];
    const float* gnb = (const float*)d_in[2];
    const float* wq  = (const float*)d_in[3];
    const float* bq  = (const float*)d_in[4];
    const float* wk  = (const float*)d_in[5];
    const float* bk  = (const float*)d_in[6];
    const float* wv  = (const float*)d_in[7];
    const float* bv  = (const float*)d_in[8];
    const float* wp  = (const float*)d_in[9];
    const float* bp  = (const float*)d_in[10];
    float* out = (float*)d_out;
    char*  ws  = (char*)d_ws;

    // workspace layout (~56 MB)
    float* raw = (float*)(ws + 0);                   // 2 KB  gn stat partials [64][4][2]
    float* bqk = (float*)(ws + 8192);                // 4 KB
    uchar* Wb  = (uchar*)(ws + 65536);               // 1 MB  [4][512][512] fp8 (x16)
    uchar* Hn  = (uchar*)(ws + (2ull  << 20));       // 4 MB  [2][4096][512] fp8
    uchar* QK8 = (uchar*)(ws + (8ull  << 20));       // 8 MB  [2][4096][1024] fp8 (Q|K)
    uchar* V8  = (uchar*)(ws + (16ull << 20));       // 4 MB  [2][512][4096] fp8
    uchar* Ot8 = (uchar*)(ws + (20ull << 20));       // 4 MB  [2][4096][512] fp8 (x16)
    uchar* Sb  = (uchar*)(ws + (24ull << 20));       // 32 MB [2][4096][4096] fp8 (S*16 -> P*256)

    prep_stats<<<PREP_BLOCKS + 256, 256, 0, stream>>>(wq, wk, wv, wp, bq, bk, x, Wb, bqk, raw);
    gn_apply<<<dim3(N_/64, C_/64, B_), 256, 0, stream>>>(x, raw, gnw, gnb, Hn);

    const long long sHn = (long long)N_ * C_;        // bytes (fp8)
    const long long sQK = (long long)N_ * 1024;
    const long long sV  = (long long)C_ * N_;
    const long long sS  = (long long)N_ * N_;

    // QK fused: [4096,1024] = (Hn @ [Wq;Wk]^T)/16 + bqk -> fp8   (512 blocks)
    gemm_nt8<128,1,3,512,0><<<dim3(8, 32, 2), 256, 0, stream>>>(
        Hn, C_, sHn, Wb, C_, 0, QK8, 1024, sQK, bqk, nullptr, 1.f/16.f);
    // V: [512,4096] = (Wv @ Hn^T)/16 + bv -> fp8   (512 blocks)
    gemm_nt8<64,2,3,512,0><<<dim3(32, 8, 2), 256, 0, stream>>>(
        Wb + 2*WN, C_, 0, Hn, C_, sHn, V8, N_, sV, bv, nullptr, 1.f/16.f);

    // S*16 = Q @ K^T * (scale*16) -> fp8, both batches (2048 blocks, XCD-swizzled)
    const float alphaS = 0.044194173824159216f * 16.f;   // 512^-0.5 * 16
    gemm_nt8<128,0,3,512,2><<<2048, 256, 0, stream>>>(
        QK8, 1024, sQK, QK8 + 512, 1024, sQK, Sb, N_, sS, nullptr, nullptr, alphaS);
    // softmax rows: fp8 in/out in place (2048 blocks)
    softmax_rows8<<<B_*N_/4, 256, 0, stream>>>(Sb);
    // Ot = (P8 @ V8^T) * 16/256 -> fp8 (x16)  (512 blocks, XCD-swizzled flat grid)
    gemm_nt8<64,0,3,4096,1><<<512, 256, 0, stream>>>(
        Sb, N_, sS, V8, N_, sV, Ot8, C_, sHn, nullptr, nullptr, 1.f/16.f);
    // out[b,o,n] = x + (Wp @ Ot^T)/256 + bp   (512 blocks)
    gemm_nt8<64,2,2,512,0><<<dim3(32, 8, 2), 256, 0, stream>>>(
        Wb + 3*WN, C_, 0, Ot8, C_, sHn, out, N_, (long long)C_*N_, bp, x, 1.f/256.f);
}